// Round 7
// baseline (495.744 us; speedup 1.0000x reference)
//
#include <hip/hip_runtime.h>
#include <hip/hip_fp16.h>
#include <stdint.h>

// Problem constants
#define BS 6
#define NQ 4096
#define NH 8
#define EMB 256
#define LTOT 19560
#define ROWS_V 117360
#define ROWS_VP 117376          // padded to 917*128
#define ROWS_Q 24576            // 192*128
#define VB2 1834                // vgemm blocks (917 M-tiles x 2 N-halves)
#define QB 1152                 // qgemm blocks (192 M x 6 N)

typedef __attribute__((ext_vector_type(8))) short bf16x8;
typedef __attribute__((ext_vector_type(4))) float floatx4;
typedef __attribute__((ext_vector_type(8))) unsigned short ushort8v;

__device__ __forceinline__ ushort f2bf(float f) {
    union { float f; uint32_t i; } c; c.f = f;
    uint32_t r = c.i + 0x7FFFu + ((c.i >> 16) & 1u);   // round-to-nearest-even
    return (ushort)(r >> 16);
}
__device__ __forceinline__ ushort f2h(float f) {
    __half h = __float2half(f);                        // RTE
    union { __half h; ushort u; } c; c.h = h; return c.u;
}
__device__ __forceinline__ float h2f(ushort u) {
    union { ushort u; __half h; } c; c.u = u; return __half2float(c.h);
}
// packed f32x2 -> bf16x2 (RNE), single VALU op; matches f2bf numerics
__device__ __forceinline__ uint32_t cvtpk(float a, float b) {
    uint32_t r;
    asm("v_cvt_pk_bf16_f32 %0, %1, %2" : "=v"(r) : "v"(a), "v"(b));
    return r;
}

__device__ __forceinline__ void gll16(const ushort* g, ushort* l) {
    __builtin_amdgcn_global_load_lds(
        (const __attribute__((address_space(1))) void*)g,
        (__attribute__((address_space(3))) void*)l, 16, 0, 0);
}

// compile-time broadcast of lane L (within each 4-lane group) via ds_swizzle
template<int L>
__device__ __forceinline__ float bcastf(float x) {
    return __int_as_float(
        __builtin_amdgcn_ds_swizzle(__float_as_int(x), 0x1C | (L << 5)));
}
template<int L>
__device__ __forceinline__ uint32_t bcastu(uint32_t x) {
    return (uint32_t)__builtin_amdgcn_ds_swizzle((int)x, 0x1C | (L << 5));
}

// gfx950 mixed-precision FMA: acc = f32(w) * f16half(u) + acc
__device__ __forceinline__ void fmx_lo(float& acc, float w, uint32_t u) {
    asm("v_fma_mix_f32 %0, %1, %2, %0 op_sel:[0,0,0] op_sel_hi:[0,1,0]"
        : "+v"(acc) : "v"(w), "v"(u));
}
__device__ __forceinline__ void fmx_hi(float& acc, float w, uint32_t u) {
    asm("v_fma_mix_f32 %0, %1, %2, %0 op_sel:[0,1,0] op_sel_hi:[0,1,0]"
        : "+v"(acc) : "v"(w), "v"(u));
}

// ---------------------------------------------------------------------------
// Fused weight prep. Wvt and Wq are stored PRE-SWIZZLED (ushort idx ^=
// (row&7)<<3) so that linear global_load_lds staging + swizzled ds_read in
// `front` is bank-conflict-free. Wot stays linear (gemm_bt path unchanged).
// ---------------------------------------------------------------------------
__global__ __launch_bounds__(256) void prep(
    const float* __restrict__ W_val, const float* __restrict__ W_off,
    const float* __restrict__ W_attn, const float* __restrict__ W_out,
    const float* __restrict__ b_off, const float* __restrict__ b_attn,
    ushort* __restrict__ Wvt, ushort* __restrict__ Wq,
    ushort* __restrict__ Wot, float* __restrict__ bcat)
{
    int id = blockIdx.x * 256 + threadIdx.x;
    if (id < 65536) {
        int n = id >> 8, k = id & 255;
        Wvt[id ^ ((n & 7) << 3)] = f2bf(W_val[k * 256 + n]);
        return;
    }
    id -= 65536;
    if (id < 131072) {
        int n = id >> 8, k = id & 255;
        Wq[id ^ ((n & 7) << 3)] = f2bf(W_off[k * 512 + n]);
        return;
    }
    id -= 131072;
    if (id < 65536) {
        int n = id >> 8, k = id & 255;
        Wq[131072 + (id ^ ((n & 7) << 3))] = f2bf(W_attn[k * 256 + n]);
        return;
    }
    id -= 65536;
    if (id < 65536) {
        int n = id >> 8, k = id & 255;
        Wot[id] = f2bf(W_out[k * 256 + n]);
        return;
    }
    id -= 65536;
    if (id < 768) bcat[id] = (id < 512) ? b_off[id] : b_attn[id - 512];
}

// ---------------------------------------------------------------------------
// Unified front GEMM, barrier-free K-loop:
//  - B tile (128 N-rows x 256 K) staged ONCE into LDS (64 KB, XOR-swizzled
//    via pre-swizzled global source), one barrier total.
//  - A fragments loaded directly from global fp32 per K-step, packed to bf16
//    with v_cvt_pk_bf16_f32; L1 absorbs the 4-wave redundancy.
//  blocks [0, VB2):  v = value @ Wvt^T + b_val -> fp16   (917 M x 2 N, N inner)
//  blocks [VB2, +QB): qp = query @ Wq^T + bcat -> f16    (192 M x 6 N, N inner)
// 512 threads = 8 waves (2M x 4N), per-wave tile 64x32, acc[4][2].
// ---------------------------------------------------------------------------
__global__ __launch_bounds__(512, 4) void front(
    const float* __restrict__ value,  // ROWS_V x 256 fp32
    const float* __restrict__ query,  // ROWS_Q x 256 fp32
    const ushort* __restrict__ Wvt,   // 256 x 256 bf16 (pre-swizzled)
    const ushort* __restrict__ Wq,    // 768 x 256 bf16 (pre-swizzled)
    const float* __restrict__ b_val,  // 256
    const float* __restrict__ bcat,   // 768
    ushort* __restrict__ v_out,       // ROWS_VP x 256 fp16
    ushort* __restrict__ qp_out)      // ROWS_Q x 768 f16
{
    __shared__ ushort Bs[128 * 256];  // 64 KB

    const int t = threadIdx.x;
    const int w = t >> 6;
    const int lane = t & 63;
    const int bid = blockIdx.x;

    const float* Ap;
    const ushort* Bsrc;
    const float* bias;
    ushort* Cout;
    int Nout, bm, bn, Mrows;
    if (bid < VB2) {
        int m = bid >> 1, nh = bid & 1;          // N-half inner: A L2-reuse
        bm = m * 128; bn = nh * 128;
        Ap = value; Bsrc = Wvt + bn * 256; bias = b_val; Cout = v_out;
        Nout = 256; Mrows = ROWS_V;
    } else {
        int qb = bid - VB2;
        int m = qb / 6, nh = qb - m * 6;         // bn inner: A L2-reuse
        bm = m * 128; bn = nh * 128;
        Ap = query; Bsrc = Wq + bn * 256; bias = bcat; Cout = qp_out;
        Nout = 768; Mrows = ROWS_Q;
    }

    // stage whole B tile (64 KB) linearly; source is pre-swizzled
    #pragma unroll
    for (int i = 0; i < 8; ++i)
        gll16(Bsrc + i * 4096 + t * 8, &Bs[i * 4096 + t * 8]);
    __syncthreads();   // drains vmcnt; only barrier in the kernel

    const int wm = (w >> 2) * 64;        // 2 M-groups
    const int wn = (w & 3) * 32;         // 4 N-groups
    const int ks = (lane >> 4) * 8;      // K sub-slice (elements)
    const int arow0 = bm + wm + (lane & 15);

    // B read bases (swizzle XOR applied per access: bits 3-5 of ushort idx)
    const int nl0 = wn + (lane & 15);    // frag j adds j*16 (doesn't change &7)
    const int bsw = (nl0 & 7) << 3;
    int bbase[2];
    #pragma unroll
    for (int j = 0; j < 2; ++j)
        bbase[j] = (nl0 + j * 16) * 256 + ks;

    const float* arow_p[4];
    bool rok[4];
    #pragma unroll
    for (int i = 0; i < 4; ++i) {
        int r = arow0 + i * 16;
        rok[i] = r < Mrows;
        arow_p[i] = Ap + (size_t)r * 256 + ks;
    }

    floatx4 acc[4][2] = {};

    for (int kt = 0; kt < 256; kt += 32) {
        bf16x8 a[4], b[2];
        #pragma unroll
        for (int i = 0; i < 4; ++i) {
            float4 f0, f1;
            if (rok[i]) {
                f0 = *(const float4*)(arow_p[i] + kt);
                f1 = *(const float4*)(arow_p[i] + kt + 4);
            } else {
                f0 = make_float4(0.f, 0.f, 0.f, 0.f); f1 = f0;
            }
            union { uint32_t u[4]; bf16x8 v; } cc;
            cc.u[0] = cvtpk(f0.x, f0.y);
            cc.u[1] = cvtpk(f0.z, f0.w);
            cc.u[2] = cvtpk(f1.x, f1.y);
            cc.u[3] = cvtpk(f1.z, f1.w);
            a[i] = cc.v;
        }
        #pragma unroll
        for (int j = 0; j < 2; ++j)
            b[j] = *(const bf16x8*)&Bs[(bbase[j] + kt) ^ bsw];
        #pragma unroll
        for (int i = 0; i < 4; ++i)
            #pragma unroll
            for (int j = 0; j < 2; ++j)
                acc[i][j] = __builtin_amdgcn_mfma_f32_16x16x32_bf16(
                    a[i], b[j], acc[i][j], 0, 0, 0);
    }

    const int crow = (lane >> 4) * 4;
    const int ccol = lane & 15;
    #pragma unroll
    for (int j = 0; j < 2; ++j) {
        int gcol = bn + wn + j * 16 + ccol;
        float bv = bias[gcol];
        #pragma unroll
        for (int i = 0; i < 4; ++i) {
            #pragma unroll
            for (int r = 0; r < 4; ++r) {
                int grow = bm + wm + i * 16 + crow + r;
                if (grow < Mrows)
                    Cout[(size_t)grow * Nout + gcol] = f2h(acc[i][j][r] + bv);
            }
        }
    }
}

// ---------------------------------------------------------------------------
// bf16 MFMA GEMM (m97 structure): C[M,N] = A[M,256] @ Bt[N,256]^T + bias
// fp32 output. 128x128 tile, 256 threads = 4 waves.  (out projection)
// ---------------------------------------------------------------------------
__global__ __launch_bounds__(256) void gemm_bt(
    const ushort* __restrict__ A,    // Mpad x 256 bf16
    const ushort* __restrict__ Bt,   // N x 256 bf16 (linear)
    const float* __restrict__ bias,  // N
    float* __restrict__ C, int M, int N)
{
    constexpr int K = 256;
    __shared__ ushort As[128 * 32];
    __shared__ ushort Bs[128 * 32];

    const int t = threadIdx.x;
    const int w = t >> 6;
    const int lane = t & 63;
    const int bm = blockIdx.x * 128;
    const int bn = blockIdx.y * 128;
    const int wm = (w >> 1) * 64;
    const int wn = (w & 1) * 64;

    floatx4 acc[4][4] = {};

    const int srow = lane >> 2;
    const int scol = (lane & 3) * 8;
    const ushort* Ag0 = A + (size_t)(bm + (w * 2 + 0) * 16 + srow) * K + scol;
    const ushort* Ag1 = A + (size_t)(bm + (w * 2 + 1) * 16 + srow) * K + scol;
    const ushort* Bg0 = Bt + (size_t)(bn + (w * 2 + 0) * 16 + srow) * K + scol;
    const ushort* Bg1 = Bt + (size_t)(bn + (w * 2 + 1) * 16 + srow) * K + scol;
    ushort* Al0 = &As[(w * 2 + 0) * 512];
    ushort* Al1 = &As[(w * 2 + 1) * 512];
    ushort* Bl0 = &Bs[(w * 2 + 0) * 512];
    ushort* Bl1 = &Bs[(w * 2 + 1) * 512];

    const ushort* apt = &As[(wm + (lane & 15)) * 32 + (lane >> 4) * 8];
    const ushort* bpt = &Bs[(wn + (lane & 15)) * 32 + (lane >> 4) * 8];

    for (int kt = 0; kt < K; kt += 32) {
        __syncthreads();
        gll16(Ag0 + kt, Al0);
        gll16(Ag1 + kt, Al1);
        gll16(Bg0 + kt, Bl0);
        gll16(Bg1 + kt, Bl1);
        __syncthreads();

        bf16x8 a[4], b[4];
        #pragma unroll
        for (int i = 0; i < 4; ++i) {
            a[i] = *(const bf16x8*)(apt + i * 16 * 32);
            b[i] = *(const bf16x8*)(bpt + i * 16 * 32);
        }
        #pragma unroll
        for (int i = 0; i < 4; ++i)
            #pragma unroll
            for (int j = 0; j < 4; ++j)
                acc[i][j] = __builtin_amdgcn_mfma_f32_16x16x32_bf16(
                    a[i], b[j], acc[i][j], 0, 0, 0);
    }

    const int crow = (lane >> 4) * 4;
    const int ccol = lane & 15;
    #pragma unroll
    for (int j = 0; j < 4; ++j) {
        int gcol = bn + wn + j * 16 + ccol;
        float bv = bias[gcol];
        #pragma unroll
        for (int i = 0; i < 4; ++i) {
            #pragma unroll
            for (int r = 0; r < 4; ++r) {
                int grow = bm + wm + i * 16 + crow + r;
                if (grow < M)
                    C[(size_t)grow * N + gcol] = acc[i][j][r] + bv;
            }
        }
    }
}

// ---------------------------------------------------------------------------
// Deformable sampling + aggregation (owner-computes + fma_mix + saddr),
// (pixel, 256ch) fp16 v layout. 48 KB LDS ballast caps residency at
// 3 blocks/CU. XCD-chunked block swizzle for per-L2 v-window locality.
// qp is f16 (1536 B/row): [0:512) offsets, [512:768) logits.
// ---------------------------------------------------------------------------
__global__ __launch_bounds__(256) void sampler4(
    const ushort* __restrict__ v,    // (BS, LTOT, 256) fp16
    const ushort* __restrict__ qp,   // (BS*NQ, 768) f16
    const float* __restrict__ ref,   // (BS*NQ, 4, 2)
    ushort* __restrict__ agg)        // (BS*NQ, 256) bf16
{
    __shared__ char ballast[49152];          // occupancy cap: 3 blocks/CU
    if (blockIdx.x > 0x7FFFFFF0u) {          // never true; unprovable -> kept
        ballast[threadIdx.x] = (char)threadIdx.x;
        agg[0] = (ushort)ballast[(threadIdx.x * 37) & 4095];
    }

    // XCD-chunked swizzle: 3072 blocks = 8 XCDs * 384; bijective
    const int bid = (blockIdx.x & 7) * 384 + (blockIdx.x >> 3);

    const int tid = threadIdx.x;
    const int g = bid * 64 + (tid >> 2);          // (b*NQ+q)*8 + h
    const int st = tid & 3;                        // this lane owns level st
    const int h = g & 7;
    const int bq = g >> 3;
    const int b = bid >> 9;                        // 512 blocks/batch

    // own level dims
    const int Wl = 160 >> st;
    const int Hl = (st == 3) ? 12 : (92 >> st);
    const int Sl = (st == 0) ? 0 : (st == 1) ? 14720 : (st == 2) ? 18400 : 19320;

    const ushort* qrow = qp + (size_t)bq * 768;

    // own level's 8 points -> pre-scaled pixel coords
    float px[8], py[8];
    {
        ushort8v uo0 = *(const ushort8v*)(qrow + h * 64 + st * 16);
        ushort8v uo1 = *(const ushort8v*)(qrow + h * 64 + st * 16 + 8);
        float2 rf = *(const float2*)(ref + (size_t)bq * 8 + st * 2);
        const float fW = (float)Wl, fH = (float)Hl;
        #pragma unroll
        for (int i = 0; i < 4; ++i) {
            px[i]     = fmaf(rf.x, fW, h2f(uo0[2 * i]))     - 0.5f;
            py[i]     = fmaf(rf.y, fH, h2f(uo0[2 * i + 1])) - 0.5f;
            px[i + 4] = fmaf(rf.x, fW, h2f(uo1[2 * i]))     - 0.5f;
            py[i + 4] = fmaf(rf.y, fH, h2f(uo1[2 * i + 1])) - 0.5f;
        }
    }

    // fused softmax over 32 logits (8 per lane = own level, width-4 group)
    float a8[8];
    {
        ushort8v ul = *(const ushort8v*)(qrow + 512 + h * 32 + st * 8);
        #pragma unroll
        for (int i = 0; i < 8; ++i) a8[i] = h2f(ul[i]);
        float m = a8[0];
        #pragma unroll
        for (int i = 1; i < 8; ++i) m = fmaxf(m, a8[i]);
        m = fmaxf(m, __shfl_xor(m, 1, 4));
        m = fmaxf(m, __shfl_xor(m, 2, 4));
        float s = 0.f;
        #pragma unroll
        for (int i = 0; i < 8; ++i) { a8[i] = __expf(a8[i] - m); s += a8[i]; }
        s += __shfl_xor(s, 1, 4);
        s += __shfl_xor(s, 2, 4);
        float inv = 1.f / s;
        #pragma unroll
        for (int i = 0; i < 8; ++i) a8[i] *= inv;
    }

    // SGPR-uniform batch base; per-lane (head, channel-slice) byte offset
    const char* vb = (const char*)(v + (size_t)b * (LTOT * EMB));
    const uint32_t coffB = (uint32_t)(h * 64 + st * 16);   // bytes

    float acc[8] = {0.f, 0.f, 0.f, 0.f, 0.f, 0.f, 0.f, 0.f};

    #pragma unroll
    for (int idx = 0; idx < 8; ++idx) {
        // ---- owner math: bilinear weights + row byte-offsets, own point ----
        float px_ = px[idx], py_ = py[idx];
        float x0f = floorf(px_), y0f = floorf(py_);
        float wx = px_ - x0f, wy = py_ - y0f;
        int x0 = (int)x0f, y0 = (int)y0f;
        int x1 = x0 + 1, y1 = y0 + 1;
        float vx0 = ((uint32_t)x0 < (uint32_t)Wl) ? 1.f : 0.f;
        float vx1 = ((uint32_t)x1 < (uint32_t)Wl) ? 1.f : 0.f;
        float vy0 = ((uint32_t)y0 < (uint32_t)Hl) ? 1.f : 0.f;
        float vy1 = ((uint32_t)y1 < (uint32_t)Hl) ? 1.f : 0.f;
        int cx0 = min(max(x0, 0), Wl - 1);
        int cx1 = min(max(x1, 0), Wl - 1);
        int cy0 = min(max(y0, 0), Hl - 1);
        int cy1 = min(max(y1, 0), Hl - 1);
        float aw = a8[idx];
        float omx = 1.f - wx, omy = 1.f - wy;
        float omya = omy * aw, wya = wy * aw;
        float w00 = omx * omya * (vx0 * vy0);
        float w10 = wx  * omya * (vx1 * vy0);
        float w01 = omx * wya  * (vx0 * vy1);
        float w11 = wx  * wya  * (vx1 * vy1);
        int r0 = Sl + cy0 * Wl;
        int r1 = Sl + cy1 * Wl;
        uint32_t e00 = (uint32_t)(r0 + cx0) << 9;   // pixel-row * 512 bytes
        uint32_t e10 = (uint32_t)(r0 + cx1) << 9;
        uint32_t e01 = (uint32_t)(r1 + cx0) << 9;
        uint32_t e11 = (uint32_t)(r1 + cx1) << 9;

        // ---- consume all 4 levels' points (broadcast from lane L) ----
        #define ACCMIX(w_, c_) \
            fmx_lo(acc[0], w_, c_.x); fmx_hi(acc[1], w_, c_.x); \
            fmx_lo(acc[2], w_, c_.y); fmx_hi(acc[3], w_, c_.y); \
            fmx_lo(acc[4], w_, c_.z); fmx_hi(acc[5], w_, c_.z); \
            fmx_lo(acc[6], w_, c_.w); fmx_hi(acc[7], w_, c_.w);
        #define DO_LEVEL(L) { \
            float W00 = bcastf<L>(w00), W10 = bcastf<L>(w10); \
            float W01 = bcastf<L>(w01), W11 = bcastf<L>(w11); \
            uint32_t E00 = bcastu<L>(e00), E10 = bcastu<L>(e10); \
            uint32_t E01 = bcastu<L>(e01), E11 = bcastu<L>(e11); \
            uint4 c00 = *(const uint4*)(vb + (E00 + coffB)); \
            uint4 c10 = *(const uint4*)(vb + (E10 + coffB)); \
            uint4 c01 = *(const uint4*)(vb + (E01 + coffB)); \
            uint4 c11 = *(const uint4*)(vb + (E11 + coffB)); \
            ACCMIX(W00, c00); ACCMIX(W10, c10); \
            ACCMIX(W01, c01); ACCMIX(W11, c11); }
        DO_LEVEL(0)
        DO_LEVEL(1)
        DO_LEVEL(2)
        DO_LEVEL(3)
        #undef DO_LEVEL
        #undef ACCMIX
    }

    ushort8v r;
    #pragma unroll
    for (int i = 0; i < 8; ++i) r[i] = f2bf(acc[i]);
    *(ushort8v*)(agg + (size_t)bq * 256 + h * 32 + st * 8) = r;
}

// ---------------------------------------------------------------------------
// Launch
// ---------------------------------------------------------------------------
extern "C" void kernel_launch(void* const* d_in, const int* in_sizes, int n_in,
                              void* d_out, int out_size, void* d_ws, size_t ws_size,
                              hipStream_t stream) {
    const float* query  = (const float*)d_in[0];
    const float* value  = (const float*)d_in[1];
    const float* refpts = (const float*)d_in[2];
    const float* W_off  = (const float*)d_in[4];
    const float* b_off  = (const float*)d_in[5];
    const float* W_attn = (const float*)d_in[6];
    const float* b_attn = (const float*)d_in[7];
    const float* W_val  = (const float*)d_in[8];
    const float* b_val  = (const float*)d_in[9];
    const float* W_out  = (const float*)d_in[10];
    const float* b_out  = (const float*)d_in[11];
    float* out = (float*)d_out;

    char* ws = (char*)d_ws;
    // layout (bytes):
    ushort* v_bf   = (ushort*)(ws);                     // 117376x256 fp16 = 60,096,512
    ushort* qp     = (ushort*)(ws + 72679424ull);       // 24576x768 f16 = 37,748,736
    ushort* agg_bf = (ushort*)(ws + 148176896ull);      // 24576x256 bf16 = 12,582,912
    ushort* Wvt    = (ushort*)(ws + 160759808ull);      // 131,072
    ushort* Wq     = (ushort*)(ws + 160890880ull);      // 768x256 bf16 = 393,216
    ushort* Wot    = (ushort*)(ws + 161284096ull);      // 131,072
    float*  bcat   = (float*) (ws + 161415168ull);      // 3,072

    // weight preprocessing (Wvt/Wq pre-swizzled for front's LDS path)
    prep<<<1283, 256, 0, stream>>>(W_val, W_off, W_attn, W_out,
                                   b_off, b_attn, Wvt, Wq, Wot, bcat);

    // 1+2. v GEMM and qp GEMM in one barrier-free launch
    front<<<VB2 + QB, 512, 0, stream>>>(
        value, query, Wvt, Wq, b_val, bcat, v_bf, qp);

    // 3. sampling + softmax + aggregation -> bf16 agg
    sampler4<<<(ROWS_Q * NH) / 64, 256, 0, stream>>>(
        v_bf, qp, refpts, agg_bf);

    // 4. out = agg @ W_out + b_out (bf16 MFMA, fp32 out)
    gemm_bt<<<dim3(ROWS_Q / 128, 2), 256, 0, stream>>>(
        agg_bf, Wot, b_out, out, ROWS_Q, 256);
}

// Round 8
// 423.953 us; speedup vs baseline: 1.1693x; 1.1693x over previous
//
#include <hip/hip_runtime.h>
#include <hip/hip_fp16.h>
#include <stdint.h>

// Problem constants
#define BS 6
#define NQ 4096
#define NH 8
#define EMB 256
#define LTOT 19560
#define ROWS_V 117360
#define ROWS_VP 117376          // padded to 917*128
#define ROWS_Q 24576            // 192*128
#define VB 1834                 // vgemm blocks (64-row tiles of ROWS_VP)
#define QB3 1152                // qgemm blocks (384 M x 3 N)

typedef __attribute__((ext_vector_type(8))) short bf16x8;
typedef __attribute__((ext_vector_type(4))) float floatx4;
typedef __attribute__((ext_vector_type(8))) unsigned short ushort8v;

__device__ __forceinline__ ushort f2bf(float f) {
    union { float f; uint32_t i; } c; c.f = f;
    uint32_t r = c.i + 0x7FFFu + ((c.i >> 16) & 1u);   // round-to-nearest-even
    return (ushort)(r >> 16);
}
__device__ __forceinline__ ushort f2h(float f) {
    __half h = __float2half(f);                        // RTE
    union { __half h; ushort u; } c; c.h = h; return c.u;
}
__device__ __forceinline__ float h2f(ushort u) {
    union { ushort u; __half h; } c; c.u = u; return __half2float(c.h);
}
// packed f32x2 -> bf16x2 (RNE), single VALU op; matches f2bf numerics
__device__ __forceinline__ uint32_t cvtpk(float a, float b) {
    uint32_t r;
    asm("v_cvt_pk_bf16_f32 %0, %1, %2" : "=v"(r) : "v"(a), "v"(b));
    return r;
}

__device__ __forceinline__ void gll16(const ushort* g, ushort* l) {
    __builtin_amdgcn_global_load_lds(
        (const __attribute__((address_space(1))) void*)g,
        (__attribute__((address_space(3))) void*)l, 16, 0, 0);
}

// compile-time broadcast of lane L (within each 4-lane group) via ds_swizzle
template<int L>
__device__ __forceinline__ float bcastf(float x) {
    return __int_as_float(
        __builtin_amdgcn_ds_swizzle(__float_as_int(x), 0x1C | (L << 5)));
}
template<int L>
__device__ __forceinline__ uint32_t bcastu(uint32_t x) {
    return (uint32_t)__builtin_amdgcn_ds_swizzle((int)x, 0x1C | (L << 5));
}

// gfx950 mixed-precision FMA: acc = f32(w) * f16half(u) + acc
__device__ __forceinline__ void fmx_lo(float& acc, float w, uint32_t u) {
    asm("v_fma_mix_f32 %0, %1, %2, %0 op_sel:[0,0,0] op_sel_hi:[0,1,0]"
        : "+v"(acc) : "v"(w), "v"(u));
}
__device__ __forceinline__ void fmx_hi(float& acc, float w, uint32_t u) {
    asm("v_fma_mix_f32 %0, %1, %2, %0 op_sel:[0,1,0] op_sel_hi:[0,1,0]"
        : "+v"(acc) : "v"(w), "v"(u));
}

// ---------------------------------------------------------------------------
// Fused weight prep (linear layouts; B is consumed directly from L2 in front)
// ---------------------------------------------------------------------------
__global__ __launch_bounds__(256) void prep(
    const float* __restrict__ W_val, const float* __restrict__ W_off,
    const float* __restrict__ W_attn, const float* __restrict__ W_out,
    const float* __restrict__ b_off, const float* __restrict__ b_attn,
    ushort* __restrict__ Wvt, ushort* __restrict__ Wq,
    ushort* __restrict__ Wot, float* __restrict__ bcat)
{
    int id = blockIdx.x * 256 + threadIdx.x;
    if (id < 65536) {
        int n = id >> 8, k = id & 255;
        Wvt[id] = f2bf(W_val[k * 256 + n]);
        return;
    }
    id -= 65536;
    if (id < 131072) {
        int n = id >> 8, k = id & 255;
        Wq[id] = f2bf(W_off[k * 512 + n]);
        return;
    }
    id -= 131072;
    if (id < 65536) {
        int n = id >> 8, k = id & 255;
        Wq[131072 + id] = f2bf(W_attn[k * 256 + n]);
        return;
    }
    id -= 65536;
    if (id < 65536) {
        int n = id >> 8, k = id & 255;
        Wot[id] = f2bf(W_out[k * 256 + n]);
        return;
    }
    id -= 65536;
    if (id < 768) bcat[id] = (id < 512) ? b_off[id] : b_attn[id - 512];
}

// ---------------------------------------------------------------------------
// Unified front GEMM v3:
//  - A block-tile (64 rows x 256 K) bulk-loaded fp32 (16 float4/thread issued
//    back-to-back), cvt_pk -> bf16, XOR-swizzled into 32 KB LDS. Load latency
//    paid ONCE per block.
//  - B fragments read directly from global (weights are L2-hot: every block
//    reads the same 128-384 KB). NO LDS for B, only 2 barriers per kernel.
//  blocks [0, VB):   v = value @ Wvt^T + b_val -> fp16   (full N=256/block)
//  blocks [VB,+QB3): qp = query @ Wq^T + bcat -> f16     (384 M x 3 N-tiles)
// 256 threads = 4 waves (1M x 4N), wave tile 64x64, acc[4][4].
// ---------------------------------------------------------------------------
__global__ __launch_bounds__(256, 3) void front(
    const float* __restrict__ value,  // ROWS_V x 256 fp32
    const float* __restrict__ query,  // ROWS_Q x 256 fp32
    const ushort* __restrict__ Wvt,   // 256 x 256 bf16 (linear)
    const ushort* __restrict__ Wq,    // 768 x 256 bf16 (linear)
    const float* __restrict__ b_val,  // 256
    const float* __restrict__ bcat,   // 768
    ushort* __restrict__ v_out,       // ROWS_VP x 256 fp16
    ushort* __restrict__ qp_out)      // ROWS_Q x 768 f16
{
    __shared__ ushort As[64 * 256];   // 32 KB, XOR-swizzled (idx ^ (row&7)<<3)

    const int t = threadIdx.x;
    const int w = t >> 6;
    const int lane = t & 63;
    const int bid = blockIdx.x;

    const float* Ap; const ushort* Bt; const float* bias;
    ushort* Cout; int Nout, bm, bn, Mrows;
    if (bid < VB) {
        bm = bid * 64; bn = 0;
        Ap = value; Bt = Wvt; bias = b_val; Cout = v_out;
        Nout = 256; Mrows = ROWS_V;
    } else {
        int qb = bid - VB;
        int m = qb / 3, nh = qb - m * 3;   // nh inner: adjacent blocks share A
        bm = m * 64; bn = nh * 256;
        Ap = query; Bt = Wq + (size_t)bn * 256; bias = bcat; Cout = qp_out;
        Nout = 768; Mrows = ROWS_Q;
    }

    // ---- A staging: thread t owns row t>>2, chunks (t&3)+4i (16B units) ----
    const int rt = t >> 2;
    const int jc = t & 3;
    const bool rv = (bm + rt) < Mrows;
    const float* Arow = Ap + (size_t)(bm + rt) * 256;
    ushort* Aw = As + rt * 256;
    const int rx = (rt & 7) << 3;          // swizzle XOR (ushort units)

    float4 fa[8], fb[8];
    #pragma unroll
    for (int i = 0; i < 4; ++i) {          // half 0: chunks 0..15
        int c = jc + i * 4;
        if (rv) {
            fa[2 * i]     = *(const float4*)(Arow + c * 8);
            fa[2 * i + 1] = *(const float4*)(Arow + c * 8 + 4);
        } else { fa[2 * i] = make_float4(0.f, 0.f, 0.f, 0.f); fa[2 * i + 1] = fa[2 * i]; }
    }
    #pragma unroll
    for (int i = 0; i < 4; ++i) {          // half 1: chunks 16..31
        int c = 16 + jc + i * 4;
        if (rv) {
            fb[2 * i]     = *(const float4*)(Arow + c * 8);
            fb[2 * i + 1] = *(const float4*)(Arow + c * 8 + 4);
        } else { fb[2 * i] = make_float4(0.f, 0.f, 0.f, 0.f); fb[2 * i + 1] = fb[2 * i]; }
    }
    #pragma unroll
    for (int i = 0; i < 4; ++i) {          // write half 0
        int c = jc + i * 4;
        union { uint32_t u[4]; ushort8v v; } cc;
        cc.u[0] = cvtpk(fa[2 * i].x,     fa[2 * i].y);
        cc.u[1] = cvtpk(fa[2 * i].z,     fa[2 * i].w);
        cc.u[2] = cvtpk(fa[2 * i + 1].x, fa[2 * i + 1].y);
        cc.u[3] = cvtpk(fa[2 * i + 1].z, fa[2 * i + 1].w);
        *(ushort8v*)(Aw + ((c * 8) ^ rx)) = cc.v;
    }
    __syncthreads();                       // half-0 A visible

    const int wn = w * 64;
    const ushort* Bw = Bt + (size_t)(wn + (lane & 15)) * 256 + (lane >> 4) * 8;
    const int ks8 = (lane >> 4) * 8;
    int arow256[4], rxr[4];
    #pragma unroll
    for (int i = 0; i < 4; ++i) {
        int row = i * 16 + (lane & 15);
        arow256[i] = row * 256;
        rxr[i] = (row & 7) << 3;
    }

    floatx4 acc[4][4] = {};

    // ---- K half 0 (kt 0..127), no barriers ----
    #pragma unroll
    for (int s = 0; s < 4; ++s) {
        int kt = s * 32;
        bf16x8 a[4], b[4];
        #pragma unroll
        for (int i = 0; i < 4; ++i)
            a[i] = *(const bf16x8*)&As[arow256[i] + (((kt + ks8)) ^ rxr[i])];
        #pragma unroll
        for (int j = 0; j < 4; ++j)
            b[j] = *(const bf16x8*)(Bw + (size_t)(j * 16) * 256 + kt);
        #pragma unroll
        for (int i = 0; i < 4; ++i)
            #pragma unroll
            for (int j = 0; j < 4; ++j)
                acc[i][j] = __builtin_amdgcn_mfma_f32_16x16x32_bf16(
                    a[i], b[j], acc[i][j], 0, 0, 0);
    }

    #pragma unroll
    for (int i = 0; i < 4; ++i) {          // write half 1 (disjoint LDS region)
        int c = 16 + jc + i * 4;
        union { uint32_t u[4]; ushort8v v; } cc;
        cc.u[0] = cvtpk(fb[2 * i].x,     fb[2 * i].y);
        cc.u[1] = cvtpk(fb[2 * i].z,     fb[2 * i].w);
        cc.u[2] = cvtpk(fb[2 * i + 1].x, fb[2 * i + 1].y);
        cc.u[3] = cvtpk(fb[2 * i + 1].z, fb[2 * i + 1].w);
        *(ushort8v*)(Aw + ((c * 8) ^ rx)) = cc.v;
    }
    __syncthreads();                       // half-1 A visible

    // ---- K half 1 (kt 128..255), no barriers ----
    #pragma unroll
    for (int s = 0; s < 4; ++s) {
        int kt = 128 + s * 32;
        bf16x8 a[4], b[4];
        #pragma unroll
        for (int i = 0; i < 4; ++i)
            a[i] = *(const bf16x8*)&As[arow256[i] + (((kt + ks8)) ^ rxr[i])];
        #pragma unroll
        for (int j = 0; j < 4; ++j)
            b[j] = *(const bf16x8*)(Bw + (size_t)(j * 16) * 256 + kt);
        #pragma unroll
        for (int i = 0; i < 4; ++i)
            #pragma unroll
            for (int j = 0; j < 4; ++j)
                acc[i][j] = __builtin_amdgcn_mfma_f32_16x16x32_bf16(
                    a[i], b[j], acc[i][j], 0, 0, 0);
    }

    // ---- epilogue ----
    const int crow = (lane >> 4) * 4;
    const int ccol = lane & 15;
    #pragma unroll
    for (int j = 0; j < 4; ++j) {
        int gcol = bn + wn + j * 16 + ccol;
        float bv = bias[gcol];
        #pragma unroll
        for (int i = 0; i < 4; ++i) {
            #pragma unroll
            for (int r = 0; r < 4; ++r) {
                int grow = bm + i * 16 + crow + r;
                if (grow < Mrows)
                    Cout[(size_t)grow * Nout + gcol] = f2h(acc[i][j][r] + bv);
            }
        }
    }
}

// ---------------------------------------------------------------------------
// bf16 MFMA GEMM (m97 structure): C[M,N] = A[M,256] @ Bt[N,256]^T + bias
// fp32 output. 128x128 tile, 256 threads = 4 waves.  (out projection)
// ---------------------------------------------------------------------------
__global__ __launch_bounds__(256) void gemm_bt(
    const ushort* __restrict__ A,    // Mpad x 256 bf16
    const ushort* __restrict__ Bt,   // N x 256 bf16 (linear)
    const float* __restrict__ bias,  // N
    float* __restrict__ C, int M, int N)
{
    constexpr int K = 256;
    __shared__ ushort As[128 * 32];
    __shared__ ushort Bs[128 * 32];

    const int t = threadIdx.x;
    const int w = t >> 6;
    const int lane = t & 63;
    const int bm = blockIdx.x * 128;
    const int bn = blockIdx.y * 128;
    const int wm = (w >> 1) * 64;
    const int wn = (w & 1) * 64;

    floatx4 acc[4][4] = {};

    const int srow = lane >> 2;
    const int scol = (lane & 3) * 8;
    const ushort* Ag0 = A + (size_t)(bm + (w * 2 + 0) * 16 + srow) * K + scol;
    const ushort* Ag1 = A + (size_t)(bm + (w * 2 + 1) * 16 + srow) * K + scol;
    const ushort* Bg0 = Bt + (size_t)(bn + (w * 2 + 0) * 16 + srow) * K + scol;
    const ushort* Bg1 = Bt + (size_t)(bn + (w * 2 + 1) * 16 + srow) * K + scol;
    ushort* Al0 = &As[(w * 2 + 0) * 512];
    ushort* Al1 = &As[(w * 2 + 1) * 512];
    ushort* Bl0 = &Bs[(w * 2 + 0) * 512];
    ushort* Bl1 = &Bs[(w * 2 + 1) * 512];

    const ushort* apt = &As[(wm + (lane & 15)) * 32 + (lane >> 4) * 8];
    const ushort* bpt = &Bs[(wn + (lane & 15)) * 32 + (lane >> 4) * 8];

    for (int kt = 0; kt < K; kt += 32) {
        __syncthreads();
        gll16(Ag0 + kt, Al0);
        gll16(Ag1 + kt, Al1);
        gll16(Bg0 + kt, Bl0);
        gll16(Bg1 + kt, Bl1);
        __syncthreads();

        bf16x8 a[4], b[4];
        #pragma unroll
        for (int i = 0; i < 4; ++i) {
            a[i] = *(const bf16x8*)(apt + i * 16 * 32);
            b[i] = *(const bf16x8*)(bpt + i * 16 * 32);
        }
        #pragma unroll
        for (int i = 0; i < 4; ++i)
            #pragma unroll
            for (int j = 0; j < 4; ++j)
                acc[i][j] = __builtin_amdgcn_mfma_f32_16x16x32_bf16(
                    a[i], b[j], acc[i][j], 0, 0, 0);
    }

    const int crow = (lane >> 4) * 4;
    const int ccol = lane & 15;
    #pragma unroll
    for (int j = 0; j < 4; ++j) {
        int gcol = bn + wn + j * 16 + ccol;
        float bv = bias[gcol];
        #pragma unroll
        for (int i = 0; i < 4; ++i) {
            #pragma unroll
            for (int r = 0; r < 4; ++r) {
                int grow = bm + wm + i * 16 + crow + r;
                if (grow < M)
                    C[(size_t)grow * N + gcol] = acc[i][j][r] + bv;
            }
        }
    }
}

// ---------------------------------------------------------------------------
// Deformable sampling + aggregation (owner-computes + fma_mix + saddr),
// (pixel, 256ch) fp16 v layout. 48 KB LDS ballast caps residency at
// 3 blocks/CU. XCD-chunked block swizzle for per-L2 v-window locality.
// qp is f16 (1536 B/row): [0:512) offsets, [512:768) logits.
// ---------------------------------------------------------------------------
__global__ __launch_bounds__(256) void sampler4(
    const ushort* __restrict__ v,    // (BS, LTOT, 256) fp16
    const ushort* __restrict__ qp,   // (BS*NQ, 768) f16
    const float* __restrict__ ref,   // (BS*NQ, 4, 2)
    ushort* __restrict__ agg)        // (BS*NQ, 256) bf16
{
    __shared__ char ballast[49152];          // occupancy cap: 3 blocks/CU
    if (blockIdx.x > 0x7FFFFFF0u) {          // never true; unprovable -> kept
        ballast[threadIdx.x] = (char)threadIdx.x;
        agg[0] = (ushort)ballast[(threadIdx.x * 37) & 4095];
    }

    // XCD-chunked swizzle: 3072 blocks = 8 XCDs * 384; bijective
    const int bid = (blockIdx.x & 7) * 384 + (blockIdx.x >> 3);

    const int tid = threadIdx.x;
    const int g = bid * 64 + (tid >> 2);          // (b*NQ+q)*8 + h
    const int st = tid & 3;                        // this lane owns level st
    const int h = g & 7;
    const int bq = g >> 3;
    const int b = bid >> 9;                        // 512 blocks/batch

    // own level dims
    const int Wl = 160 >> st;
    const int Hl = (st == 3) ? 12 : (92 >> st);
    const int Sl = (st == 0) ? 0 : (st == 1) ? 14720 : (st == 2) ? 18400 : 19320;

    const ushort* qrow = qp + (size_t)bq * 768;

    // own level's 8 points -> pre-scaled pixel coords
    float px[8], py[8];
    {
        ushort8v uo0 = *(const ushort8v*)(qrow + h * 64 + st * 16);
        ushort8v uo1 = *(const ushort8v*)(qrow + h * 64 + st * 16 + 8);
        float2 rf = *(const float2*)(ref + (size_t)bq * 8 + st * 2);
        const float fW = (float)Wl, fH = (float)Hl;
        #pragma unroll
        for (int i = 0; i < 4; ++i) {
            px[i]     = fmaf(rf.x, fW, h2f(uo0[2 * i]))     - 0.5f;
            py[i]     = fmaf(rf.y, fH, h2f(uo0[2 * i + 1])) - 0.5f;
            px[i + 4] = fmaf(rf.x, fW, h2f(uo1[2 * i]))     - 0.5f;
            py[i + 4] = fmaf(rf.y, fH, h2f(uo1[2 * i + 1])) - 0.5f;
        }
    }

    // fused softmax over 32 logits (8 per lane = own level, width-4 group)
    float a8[8];
    {
        ushort8v ul = *(const ushort8v*)(qrow + 512 + h * 32 + st * 8);
        #pragma unroll
        for (int i = 0; i < 8; ++i) a8[i] = h2f(ul[i]);
        float m = a8[0];
        #pragma unroll
        for (int i = 1; i < 8; ++i) m = fmaxf(m, a8[i]);
        m = fmaxf(m, __shfl_xor(m, 1, 4));
        m = fmaxf(m, __shfl_xor(m, 2, 4));
        float s = 0.f;
        #pragma unroll
        for (int i = 0; i < 8; ++i) { a8[i] = __expf(a8[i] - m); s += a8[i]; }
        s += __shfl_xor(s, 1, 4);
        s += __shfl_xor(s, 2, 4);
        float inv = 1.f / s;
        #pragma unroll
        for (int i = 0; i < 8; ++i) a8[i] *= inv;
    }

    // SGPR-uniform batch base; per-lane (head, channel-slice) byte offset
    const char* vb = (const char*)(v + (size_t)b * (LTOT * EMB));
    const uint32_t coffB = (uint32_t)(h * 64 + st * 16);   // bytes

    float acc[8] = {0.f, 0.f, 0.f, 0.f, 0.f, 0.f, 0.f, 0.f};

    #pragma unroll
    for (int idx = 0; idx < 8; ++idx) {
        // ---- owner math: bilinear weights + row byte-offsets, own point ----
        float px_ = px[idx], py_ = py[idx];
        float x0f = floorf(px_), y0f = floorf(py_);
        float wx = px_ - x0f, wy = py_ - y0f;
        int x0 = (int)x0f, y0 = (int)y0f;
        int x1 = x0 + 1, y1 = y0 + 1;
        float vx0 = ((uint32_t)x0 < (uint32_t)Wl) ? 1.f : 0.f;
        float vx1 = ((uint32_t)x1 < (uint32_t)Wl) ? 1.f : 0.f;
        float vy0 = ((uint32_t)y0 < (uint32_t)Hl) ? 1.f : 0.f;
        float vy1 = ((uint32_t)y1 < (uint32_t)Hl) ? 1.f : 0.f;
        int cx0 = min(max(x0, 0), Wl - 1);
        int cx1 = min(max(x1, 0), Wl - 1);
        int cy0 = min(max(y0, 0), Hl - 1);
        int cy1 = min(max(y1, 0), Hl - 1);
        float aw = a8[idx];
        float omx = 1.f - wx, omy = 1.f - wy;
        float omya = omy * aw, wya = wy * aw;
        float w00 = omx * omya * (vx0 * vy0);
        float w10 = wx  * omya * (vx1 * vy0);
        float w01 = omx * wya  * (vx0 * vy1);
        float w11 = wx  * wya  * (vx1 * vy1);
        int r0 = Sl + cy0 * Wl;
        int r1 = Sl + cy1 * Wl;
        uint32_t e00 = (uint32_t)(r0 + cx0) << 9;   // pixel-row * 512 bytes
        uint32_t e10 = (uint32_t)(r0 + cx1) << 9;
        uint32_t e01 = (uint32_t)(r1 + cx0) << 9;
        uint32_t e11 = (uint32_t)(r1 + cx1) << 9;

        // ---- consume all 4 levels' points (broadcast from lane L) ----
        #define ACCMIX(w_, c_) \
            fmx_lo(acc[0], w_, c_.x); fmx_hi(acc[1], w_, c_.x); \
            fmx_lo(acc[2], w_, c_.y); fmx_hi(acc[3], w_, c_.y); \
            fmx_lo(acc[4], w_, c_.z); fmx_hi(acc[5], w_, c_.z); \
            fmx_lo(acc[6], w_, c_.w); fmx_hi(acc[7], w_, c_.w);
        #define DO_LEVEL(L) { \
            float W00 = bcastf<L>(w00), W10 = bcastf<L>(w10); \
            float W01 = bcastf<L>(w01), W11 = bcastf<L>(w11); \
            uint32_t E00 = bcastu<L>(e00), E10 = bcastu<L>(e10); \
            uint32_t E01 = bcastu<L>(e01), E11 = bcastu<L>(e11); \
            uint4 c00 = *(const uint4*)(vb + (E00 + coffB)); \
            uint4 c10 = *(const uint4*)(vb + (E10 + coffB)); \
            uint4 c01 = *(const uint4*)(vb + (E01 + coffB)); \
            uint4 c11 = *(const uint4*)(vb + (E11 + coffB)); \
            ACCMIX(W00, c00); ACCMIX(W10, c10); \
            ACCMIX(W01, c01); ACCMIX(W11, c11); }
        DO_LEVEL(0)
        DO_LEVEL(1)
        DO_LEVEL(2)
        DO_LEVEL(3)
        #undef DO_LEVEL
        #undef ACCMIX
    }

    ushort8v r;
    #pragma unroll
    for (int i = 0; i < 8; ++i) r[i] = f2bf(acc[i]);
    *(ushort8v*)(agg + (size_t)bq * 256 + h * 32 + st * 8) = r;
}

// ---------------------------------------------------------------------------
// Launch
// ---------------------------------------------------------------------------
extern "C" void kernel_launch(void* const* d_in, const int* in_sizes, int n_in,
                              void* d_out, int out_size, void* d_ws, size_t ws_size,
                              hipStream_t stream) {
    const float* query  = (const float*)d_in[0];
    const float* value  = (const float*)d_in[1];
    const float* refpts = (const float*)d_in[2];
    const float* W_off  = (const float*)d_in[4];
    const float* b_off  = (const float*)d_in[5];
    const float* W_attn = (const float*)d_in[6];
    const float* b_attn = (const float*)d_in[7];
    const float* W_val  = (const float*)d_in[8];
    const float* b_val  = (const float*)d_in[9];
    const float* W_out  = (const float*)d_in[10];
    const float* b_out  = (const float*)d_in[11];
    float* out = (float*)d_out;

    char* ws = (char*)d_ws;
    // layout (bytes):
    ushort* v_bf   = (ushort*)(ws);                     // 117376x256 fp16 = 60,096,512
    ushort* qp     = (ushort*)(ws + 72679424ull);       // 24576x768 f16 = 37,748,736
    ushort* agg_bf = (ushort*)(ws + 148176896ull);      // 24576x256 bf16 = 12,582,912
    ushort* Wvt    = (ushort*)(ws + 160759808ull);      // 131,072
    ushort* Wq     = (ushort*)(ws + 160890880ull);      // 768x256 bf16 = 393,216
    ushort* Wot    = (ushort*)(ws + 161284096ull);      // 131,072
    float*  bcat   = (float*) (ws + 161415168ull);      // 3,072

    // weight preprocessing (linear layouts)
    prep<<<1283, 256, 0, stream>>>(W_val, W_off, W_attn, W_out,
                                   b_off, b_attn, Wvt, Wq, Wot, bcat);

    // 1+2. v GEMM and qp GEMM in one launch (A staged once, B from L2)
    front<<<VB + QB3, 256, 0, stream>>>(
        value, query, Wvt, Wq, b_val, bcat, v_bf, qp);

    // 3. sampling + softmax + aggregation -> bf16 agg
    sampler4<<<(ROWS_Q * NH) / 64, 256, 0, stream>>>(
        v_bf, qp, refpts, agg_bf);

    // 4. out = agg @ W_out + b_out (bf16 MFMA, fp32 out)
    gemm_bt<<<dim3(ROWS_Q / 128, 2), 256, 0, stream>>>(
        agg_bf, Wot, b_out, out, ROWS_Q, 256);
}